// Round 11
// baseline (317.497 us; speedup 1.0000x reference)
//
#include <hip/hip_runtime.h>
#include <hip/hip_bf16.h>

#define N_NODES 100000
#define N_EDGES 3200000
#define IN_CH 128
#define HID 16
#define OUT_CH 64
#define BSHIFT 9
#define BNODES 512              // nodes per bucket
#define NBUCK 196               // ceil(100000/512)
#define BCAP 18000              // per-bucket colp capacity (mean 16384 + ~12 sigma)
#define TR 64                   // gemm1 rows per block

__device__ __forceinline__ unsigned short f2bf(float f) {
    union { float f; unsigned v; } t; t.f = f;
    unsigned r = t.v + 0x7FFFu + ((t.v >> 16) & 1u);   // round-to-nearest-even
    return (unsigned short)(r >> 16);
}
__device__ __forceinline__ unsigned pack2(float lo, float hi) {
    return (unsigned)f2bf(lo) | ((unsigned)f2bf(hi) << 16);
}
// accumulate 8 bf16 channels packed in a uint4 into a[0..7]
__device__ __forceinline__ void acc8(uint4 v, float* a) {
    union { unsigned u; float f; } c;
    c.u = v.x << 16;         a[0] += c.f;
    c.u = v.x & 0xffff0000u; a[1] += c.f;
    c.u = v.y << 16;         a[2] += c.f;
    c.u = v.y & 0xffff0000u; a[3] += c.f;
    c.u = v.z << 16;         a[4] += c.f;
    c.u = v.z & 0xffff0000u; a[5] += c.f;
    c.u = v.w << 16;         a[6] += c.f;
    c.u = v.w & 0xffff0000u; a[7] += c.f;
}

// ---------------- init per-bucket cursors to fixed-capacity bases ----------------
__global__ void k_init_cur(int* __restrict__ cur) {
    int t = threadIdx.x;
    if (t < NBUCK) cur[t] = t * BCAP;
}

// ---------------- pass 1: scatter packed edges into bucket runs (single pass, no hist) ----------------
__global__ __launch_bounds__(256) void k_bucket(const int* __restrict__ src, const int* __restrict__ dst,
                                                int* __restrict__ cur, unsigned* __restrict__ colp, int e) {
    __shared__ int lh[NBUCK];
    __shared__ int lb[NBUCK];
    int t = threadIdx.x;
    if (t < NBUCK) lh[t] = 0;
    __syncthreads();
    int base = blockIdx.x * 4096;
    int bk[16]; int rk[16]; unsigned pk[16];
#pragma unroll
    for (int j = 0; j < 16; ++j) {
        int idx = base + j * 256 + t;
        if (idx < e) {
            int d = dst[idx];
            int b = d >> BSHIFT;
            bk[j] = b;
            pk[j] = ((unsigned)(d & (BNODES - 1)) << 17) | (unsigned)src[idx];
            rk[j] = atomicAdd(&lh[b], 1);
        } else bk[j] = -1;
    }
    __syncthreads();
    if (t < NBUCK) { int c = lh[t]; lb[t] = c ? atomicAdd(&cur[t], c) : 0; }
    __syncthreads();
#pragma unroll
    for (int j = 0; j < 16; ++j) if (bk[j] >= 0) colp[lb[bk[j]] + rk[j]] = pk[j];
}

// ---------------- pass 2: per-bucket counting sort -> CSR (4x MLP) ----------------
__global__ __launch_bounds__(1024) void k_build(const unsigned* __restrict__ colp, const int* __restrict__ cur,
                                                int* __restrict__ col, int* __restrict__ row_ptr,
                                                int* __restrict__ deg, float* __restrict__ dinv) {
    __shared__ int cnt[BNODES];
    __shared__ int sc[BNODES];
    __shared__ int ex[BNODES];
    __shared__ int curl[BNODES];
    int b = blockIdx.x, t = threadIdx.x;
    if (t < BNODES) cnt[t] = 0;
    __syncthreads();
    int base = b * BCAP;
    int m = cur[b] - base;
    int i = t;
    for (; i + 3072 < m; i += 4096) {
        unsigned p0 = colp[base + i];
        unsigned p1 = colp[base + i + 1024];
        unsigned p2 = colp[base + i + 2048];
        unsigned p3 = colp[base + i + 3072];
        atomicAdd(&cnt[p0 >> 17], 1);
        atomicAdd(&cnt[p1 >> 17], 1);
        atomicAdd(&cnt[p2 >> 17], 1);
        atomicAdd(&cnt[p3 >> 17], 1);
    }
    for (; i < m; i += 1024) atomicAdd(&cnt[colp[base + i] >> 17], 1);
    __syncthreads();
    int v = 0;
    if (t < BNODES) { v = cnt[t]; sc[t] = v; }
    __syncthreads();
    for (int off = 1; off < BNODES; off <<= 1) {
        int x = 0;
        if (t < BNODES && t >= off) x = sc[t - off];
        __syncthreads();
        if (t < BNODES) sc[t] += x;
        __syncthreads();
    }
    if (t < BNODES) {
        ex[t] = sc[t] - v;
        curl[t] = 0;
        int node = b * BNODES + t;
        if (node < N_NODES) {
            row_ptr[node] = base + ex[t];
            deg[node] = v;
            dinv[node] = rsqrtf((float)v + 1.0f);
        }
    }
    __syncthreads();
    i = t;
    for (; i + 3072 < m; i += 4096) {
        unsigned p0 = colp[base + i];
        unsigned p1 = colp[base + i + 1024];
        unsigned p2 = colp[base + i + 2048];
        unsigned p3 = colp[base + i + 3072];
        int l0 = p0 >> 17, l1 = p1 >> 17, l2 = p2 >> 17, l3 = p3 >> 17;
        int q0 = atomicAdd(&curl[l0], 1);
        int q1 = atomicAdd(&curl[l1], 1);
        int q2 = atomicAdd(&curl[l2], 1);
        int q3 = atomicAdd(&curl[l3], 1);
        col[base + ex[l0] + q0] = (int)(p0 & 0x1FFFF);
        col[base + ex[l1] + q1] = (int)(p1 & 0x1FFFF);
        col[base + ex[l2] + q2] = (int)(p2 & 0x1FFFF);
        col[base + ex[l3] + q3] = (int)(p3 & 0x1FFFF);
    }
    for (; i < m; i += 1024) {
        unsigned pv = colp[base + i];
        int l = pv >> 17;
        int p = atomicAdd(&curl[l], 1);
        col[base + ex[l] + p] = (int)(pv & 0x1FFFF);
    }
}

// ---------------- h1' = bf16( dinv * (x @ W1) ), 64-row tile, 4 acc/thread ----------------
__global__ __launch_bounds__(256) void k_gemm1(const float* __restrict__ x,
                                               const float* __restrict__ W1,
                                               const float* __restrict__ dinv,
                                               unsigned short* __restrict__ h1p, int n) {
    __shared__ float Ws[IN_CH * HID];          // 8 KB
    __shared__ float xs[TR][IN_CH + 1];        // 33 KB, padded (row reads land in distinct banks)
    __shared__ uint4 os4[TR * HID * 2 / 16];   // 2 KB bf16 output staging
    int t = threadIdx.x;
    {   // stage W1 as float4
        const float4* w4 = reinterpret_cast<const float4*>(W1);
        float4* ws4 = reinterpret_cast<float4*>(Ws);
        for (int i = t; i < IN_CH * HID / 4; i += 256) ws4[i] = w4[i];
    }
    int row0 = blockIdx.x * TR;
    // stage x tile: 2048 float4, 8 per thread, coalesced
    for (int i = t; i < TR * IN_CH / 4; i += 256) {
        int r = i >> 5;            // 32 float4 per row
        int c4 = i & 31;
        int row = row0 + r;
        float4 v = (row < n) ? reinterpret_cast<const float4*>(x)[(size_t)row * 32 + c4]
                             : make_float4(0.f, 0.f, 0.f, 0.f);
        *reinterpret_cast<float4*>(&xs[r][c4 * 4]) = v;
    }
    __syncthreads();
    int r = t >> 4;    // 0..15
    int c = t & 15;
    float a0 = 0.f, a1 = 0.f, a2 = 0.f, a3 = 0.f;
#pragma unroll
    for (int k = 0; k < IN_CH; ++k) {
        float w = Ws[k * HID + c];
        a0 = fmaf(xs[r][k], w, a0);
        a1 = fmaf(xs[r + 16][k], w, a1);
        a2 = fmaf(xs[r + 32][k], w, a2);
        a3 = fmaf(xs[r + 48][k], w, a3);
    }
    unsigned short* os = reinterpret_cast<unsigned short*>(os4);
    int rr0 = row0 + r, rr1 = rr0 + 16, rr2 = rr0 + 32, rr3 = rr0 + 48;
    os[(r + 0)  * HID + c] = f2bf(((rr0 < n) ? dinv[rr0] : 0.f) * a0);
    os[(r + 16) * HID + c] = f2bf(((rr1 < n) ? dinv[rr1] : 0.f) * a1);
    os[(r + 32) * HID + c] = f2bf(((rr2 < n) ? dinv[rr2] : 0.f) * a2);
    os[(r + 48) * HID + c] = f2bf(((rr3 < n) ? dinv[rr3] : 0.f) * a3);
    __syncthreads();
    // coalesced uint4 write: 128 x 16 B = 64 rows x 32 B
    if (t < TR * 2) {
        int row = row0 + (t >> 1);
        if (row < n) reinterpret_cast<uint4*>(h1p)[(size_t)row * 2 + (t & 1)] = os4[t];
    }
}

// ---------------- gather layer 1: 4 threads/node (q=ch-half, p=edge-parity), shfl combine ----------------
__global__ __launch_bounds__(256) void k_gather1(const unsigned short* __restrict__ h1p,
                                                 const int* __restrict__ row_ptr,
                                                 const int* __restrict__ deg,
                                                 const float* __restrict__ dinv,
                                                 const int* __restrict__ col,
                                                 const float* __restrict__ b1,
                                                 unsigned short* __restrict__ h2p, int n) {
    int t = blockIdx.x * blockDim.x + threadIdx.x;
    int i = t >> 2;
    if (i >= n) return;
    int q = t & 1, p = (t >> 1) & 1;
    const uint4* hp = reinterpret_cast<const uint4*>(h1p);
    float a[8] = {0, 0, 0, 0, 0, 0, 0, 0};
    int j0 = row_ptr[i], j1 = j0 + deg[i];
    int j = j0 + p;
    for (; j + 6 < j1; j += 8) {
        int s0 = col[j], s1 = col[j + 2], s2 = col[j + 4], s3 = col[j + 6];
        uint4 v0 = hp[(size_t)s0 * 2 + q];
        uint4 v1 = hp[(size_t)s1 * 2 + q];
        uint4 v2 = hp[(size_t)s2 * 2 + q];
        uint4 v3 = hp[(size_t)s3 * 2 + q];
        acc8(v0, a); acc8(v1, a); acc8(v2, a); acc8(v3, a);
    }
    for (; j < j1; j += 2) acc8(hp[(size_t)col[j] * 2 + q], a);
    // combine edge-parity partners (lane^2 is same node, same q)
#pragma unroll
    for (int k = 0; k < 8; ++k) a[k] += __shfl_xor(a[k], 2);
    if (p == 0) {
        acc8(hp[(size_t)i * 2 + q], a);   // self-loop
        float di = dinv[i];
        float4 bl = *reinterpret_cast<const float4*>(&b1[q * 8]);
        float4 bh = *reinterpret_cast<const float4*>(&b1[q * 8 + 4]);
        float o[8];
        o[0] = di * fmaxf(fmaf(di, a[0], bl.x), 0.f);
        o[1] = di * fmaxf(fmaf(di, a[1], bl.y), 0.f);
        o[2] = di * fmaxf(fmaf(di, a[2], bl.z), 0.f);
        o[3] = di * fmaxf(fmaf(di, a[3], bl.w), 0.f);
        o[4] = di * fmaxf(fmaf(di, a[4], bh.x), 0.f);
        o[5] = di * fmaxf(fmaf(di, a[5], bh.y), 0.f);
        o[6] = di * fmaxf(fmaf(di, a[6], bh.z), 0.f);
        o[7] = di * fmaxf(fmaf(di, a[7], bh.w), 0.f);
        uint4 ov;
        ov.x = pack2(o[0], o[1]);
        ov.y = pack2(o[2], o[3]);
        ov.z = pack2(o[4], o[5]);
        ov.w = pack2(o[6], o[7]);
        reinterpret_cast<uint4*>(h2p)[(size_t)i * 2 + q] = ov;
    }
}

// ---------------- gather layer 2: 4 threads/node + fused (N x 16)@(16 x 64) + b2 ----------------
__global__ __launch_bounds__(256) void k_gather2_out(const unsigned short* __restrict__ h2p,
                                                     const int* __restrict__ row_ptr,
                                                     const int* __restrict__ deg,
                                                     const float* __restrict__ dinv,
                                                     const int* __restrict__ col,
                                                     const float* __restrict__ W2,
                                                     const float* __restrict__ b2,
                                                     float* __restrict__ out, int n) {
    __shared__ float Ws[HID * OUT_CH];    // 4 KB
    __shared__ float as[64][HID + 1];     // 4.4 KB
    int t = threadIdx.x;
    for (int i = t; i < HID * OUT_CH; i += 256) Ws[i] = W2[i];
    int nl = t >> 2;                       // 64 nodes/block
    int i = blockIdx.x * 64 + nl;
    int q = t & 1, p = (t >> 1) & 1;
    const uint4* hp = reinterpret_cast<const uint4*>(h2p);
    if (i < n) {
        float a[8] = {0, 0, 0, 0, 0, 0, 0, 0};
        int j0 = row_ptr[i], j1 = j0 + deg[i];
        int j = j0 + p;
        for (; j + 6 < j1; j += 8) {
            int s0 = col[j], s1 = col[j + 2], s2 = col[j + 4], s3 = col[j + 6];
            uint4 v0 = hp[(size_t)s0 * 2 + q];
            uint4 v1 = hp[(size_t)s1 * 2 + q];
            uint4 v2 = hp[(size_t)s2 * 2 + q];
            uint4 v3 = hp[(size_t)s3 * 2 + q];
            acc8(v0, a); acc8(v1, a); acc8(v2, a); acc8(v3, a);
        }
        for (; j < j1; j += 2) acc8(hp[(size_t)col[j] * 2 + q], a);
#pragma unroll
        for (int k = 0; k < 8; ++k) a[k] += __shfl_xor(a[k], 2);
        if (p == 0) {
            acc8(hp[(size_t)i * 2 + q], a);   // self
            float di = dinv[i];
#pragma unroll
            for (int k = 0; k < 8; ++k) as[nl][q * 8 + k] = di * a[k];
        }
    } else if (p == 0) {
#pragma unroll
        for (int k = 0; k < 8; ++k) as[nl][q * 8 + k] = 0.f;
    }
    __syncthreads();
    // epilogue: node nl, cols g*16 .. g*16+15
    int g = t & 3;
    float r[16];
#pragma unroll
    for (int c = 0; c < 16; ++c) r[c] = b2[g * 16 + c];
#pragma unroll
    for (int k = 0; k < HID; ++k) {
        float a = as[nl][k];
#pragma unroll
        for (int c = 0; c < 16; ++c) r[c] = fmaf(a, Ws[k * OUT_CH + g * 16 + c], r[c]);
    }
    if (i < n) {
        float* op = &out[(size_t)i * OUT_CH + g * 16];
#pragma unroll
        for (int c = 0; c < 16; c += 4)
            *reinterpret_cast<float4*>(&op[c]) = make_float4(r[c], r[c + 1], r[c + 2], r[c + 3]);
    }
}

extern "C" void kernel_launch(void* const* d_in, const int* in_sizes, int n_in,
                              void* d_out, int out_size, void* d_ws, size_t ws_size,
                              hipStream_t stream) {
    const float* x  = (const float*)d_in[0];
    const int*   ei = (const int*)d_in[1];
    const float* W1 = (const float*)d_in[2];
    const float* b1 = (const float*)d_in[3];
    const float* W2 = (const float*)d_in[4];
    const float* b2 = (const float*)d_in[5];
    float* out = (float*)d_out;

    const int* src = ei;
    const int* dst = ei + N_EDGES;

    // workspace layout (4B units)
    int*            cur     = (int*)d_ws;                          // [0, 256)
    int*            row_ptr = cur + 256;                           // [256, 100256)
    int*            deg     = row_ptr + N_NODES;                   // [100256, 200256)
    float*          dinv    = (float*)(deg + N_NODES);             // [200256, 300256)
    int*            col     = (int*)(dinv + N_NODES);              // [300256, 3828256)  196*18000
    unsigned short* h1p     = (unsigned short*)(col + NBUCK * BCAP);  // [3828256, 4628256) bf16 N*16 = 800000 words
    unsigned*       colp    = (unsigned*)((int*)h1p + 800000);     // [4628256, 8156256)  196*18000
    unsigned short* h2p     = (unsigned short*)colp;               // aliases colp (dead after k_build)

    // single-pass bucketed edge list (fixed-capacity runs; cur pre-set to b*BCAP)
    k_init_cur<<<1, 256, 0, stream>>>(cur);
    k_bucket<<<(N_EDGES + 4095) / 4096, 256, 0, stream>>>(src, dst, cur, colp, N_EDGES);
    // per-bucket counting sort -> full CSR + degrees + dinv
    k_build<<<NBUCK, 1024, 0, stream>>>(colp, cur, col, row_ptr, deg, dinv);

    // h1' = bf16(dinv * (x @ W1))
    k_gemm1<<<(N_NODES + TR - 1) / TR, 256, 0, stream>>>(x, W1, dinv, h1p, N_NODES);

    // layer 1: gather + bias + relu + pre-scale  (h2p aliases colp region; colp dead after k_build)
    k_gather1<<<((size_t)4 * N_NODES + 255) / 256, 256, 0, stream>>>(h1p, row_ptr, deg, dinv, col,
                                                                     b1, h2p, N_NODES);

    // layer 2: gather fused with final GEMM + bias
    k_gather2_out<<<(N_NODES + 63) / 64, 256, 0, stream>>>(h2p, row_ptr, deg, dinv, col, W2, b2,
                                                           out, N_NODES);
}

// Round 12
// 155.121 us; speedup vs baseline: 2.0468x; 2.0468x over previous
//
#include <hip/hip_runtime.h>
#include <hip/hip_bf16.h>

#define N_NODES 100000
#define N_EDGES 3200000
#define IN_CH 128
#define HID 16
#define OUT_CH 64
#define BSHIFT 9
#define BNODES 512              // nodes per bucket
#define NBUCK 196               // ceil(100000/512)
#define BCAP 18000              // per-bucket colp capacity (mean 16384 + ~12 sigma)
#define TR 32                   // gemm1 rows per block
#define XP 132                  // padded LDS row stride (keeps 16B align; banks 4r+4k distinct)

__device__ __forceinline__ unsigned short f2bf(float f) {
    union { float f; unsigned v; } t; t.f = f;
    unsigned r = t.v + 0x7FFFu + ((t.v >> 16) & 1u);   // round-to-nearest-even
    return (unsigned short)(r >> 16);
}
__device__ __forceinline__ unsigned pack2(float lo, float hi) {
    return (unsigned)f2bf(lo) | ((unsigned)f2bf(hi) << 16);
}
// accumulate 8 bf16 channels packed in a uint4 into a[0..7]
__device__ __forceinline__ void acc8(uint4 v, float* a) {
    union { unsigned u; float f; } c;
    c.u = v.x << 16;         a[0] += c.f;
    c.u = v.x & 0xffff0000u; a[1] += c.f;
    c.u = v.y << 16;         a[2] += c.f;
    c.u = v.y & 0xffff0000u; a[3] += c.f;
    c.u = v.z << 16;         a[4] += c.f;
    c.u = v.z & 0xffff0000u; a[5] += c.f;
    c.u = v.w << 16;         a[6] += c.f;
    c.u = v.w & 0xffff0000u; a[7] += c.f;
}

// ---------------- init per-bucket cursors to fixed-capacity bases ----------------
__global__ void k_init_cur(int* __restrict__ cur) {
    int t = threadIdx.x;
    if (t < NBUCK) cur[t] = t * BCAP;
}

// ---------------- pass 1: scatter packed edges into bucket runs (single pass, no hist) ----------------
__global__ __launch_bounds__(256) void k_bucket(const int* __restrict__ src, const int* __restrict__ dst,
                                                int* __restrict__ cur, unsigned* __restrict__ colp, int e) {
    __shared__ int lh[NBUCK];
    __shared__ int lb[NBUCK];
    int t = threadIdx.x;
    if (t < NBUCK) lh[t] = 0;
    __syncthreads();
    int base = blockIdx.x * 4096;
    int bk[16]; int rk[16]; unsigned pk[16];
#pragma unroll
    for (int j = 0; j < 16; ++j) {
        int idx = base + j * 256 + t;
        if (idx < e) {
            int d = dst[idx];
            int b = d >> BSHIFT;
            bk[j] = b;
            pk[j] = ((unsigned)(d & (BNODES - 1)) << 17) | (unsigned)src[idx];
            rk[j] = atomicAdd(&lh[b], 1);
        } else bk[j] = -1;
    }
    __syncthreads();
    if (t < NBUCK) { int c = lh[t]; lb[t] = c ? atomicAdd(&cur[t], c) : 0; }
    __syncthreads();
#pragma unroll
    for (int j = 0; j < 16; ++j) if (bk[j] >= 0) colp[lb[bk[j]] + rk[j]] = pk[j];
}

// ---------------- pass 2: per-bucket counting sort -> CSR (4x MLP) ----------------
__global__ __launch_bounds__(1024) void k_build(const unsigned* __restrict__ colp, const int* __restrict__ cur,
                                                int* __restrict__ col, int* __restrict__ row_ptr,
                                                int* __restrict__ deg, float* __restrict__ dinv) {
    __shared__ int cnt[BNODES];
    __shared__ int sc[BNODES];
    __shared__ int ex[BNODES];
    __shared__ int curl[BNODES];
    int b = blockIdx.x, t = threadIdx.x;
    if (t < BNODES) cnt[t] = 0;
    __syncthreads();
    int base = b * BCAP;
    int m = cur[b] - base;
    int i = t;
    for (; i + 3072 < m; i += 4096) {
        unsigned p0 = colp[base + i];
        unsigned p1 = colp[base + i + 1024];
        unsigned p2 = colp[base + i + 2048];
        unsigned p3 = colp[base + i + 3072];
        atomicAdd(&cnt[p0 >> 17], 1);
        atomicAdd(&cnt[p1 >> 17], 1);
        atomicAdd(&cnt[p2 >> 17], 1);
        atomicAdd(&cnt[p3 >> 17], 1);
    }
    for (; i < m; i += 1024) atomicAdd(&cnt[colp[base + i] >> 17], 1);
    __syncthreads();
    int v = 0;
    if (t < BNODES) { v = cnt[t]; sc[t] = v; }
    __syncthreads();
    for (int off = 1; off < BNODES; off <<= 1) {
        int x = 0;
        if (t < BNODES && t >= off) x = sc[t - off];
        __syncthreads();
        if (t < BNODES) sc[t] += x;
        __syncthreads();
    }
    if (t < BNODES) {
        ex[t] = sc[t] - v;
        curl[t] = 0;
        int node = b * BNODES + t;
        if (node < N_NODES) {
            row_ptr[node] = base + ex[t];
            deg[node] = v;
            dinv[node] = rsqrtf((float)v + 1.0f);
        }
    }
    __syncthreads();
    i = t;
    for (; i + 3072 < m; i += 4096) {
        unsigned p0 = colp[base + i];
        unsigned p1 = colp[base + i + 1024];
        unsigned p2 = colp[base + i + 2048];
        unsigned p3 = colp[base + i + 3072];
        int l0 = p0 >> 17, l1 = p1 >> 17, l2 = p2 >> 17, l3 = p3 >> 17;
        int q0 = atomicAdd(&curl[l0], 1);
        int q1 = atomicAdd(&curl[l1], 1);
        int q2 = atomicAdd(&curl[l2], 1);
        int q3 = atomicAdd(&curl[l3], 1);
        col[base + ex[l0] + q0] = (int)(p0 & 0x1FFFF);
        col[base + ex[l1] + q1] = (int)(p1 & 0x1FFFF);
        col[base + ex[l2] + q2] = (int)(p2 & 0x1FFFF);
        col[base + ex[l3] + q3] = (int)(p3 & 0x1FFFF);
    }
    for (; i < m; i += 1024) {
        unsigned pv = colp[base + i];
        int l = pv >> 17;
        int p = atomicAdd(&curl[l], 1);
        col[base + ex[l] + p] = (int)(pv & 0x1FFFF);
    }
}

// ---------------- h1' = bf16( dinv * (x @ W1) ), 32-row tile, b128 LDS reads ----------------
__global__ __launch_bounds__(256) void k_gemm1(const float* __restrict__ x,
                                               const float* __restrict__ W1,
                                               const float* __restrict__ dinv,
                                               unsigned short* __restrict__ h1p, int n) {
    __shared__ float Wt[HID * XP];     // W transposed: Wt[c][k], 8.4 KB
    __shared__ float xs[TR * XP];      // x tile, 16.9 KB
    int t = threadIdx.x;
    // stage W1 transposed: Wt[c*XP + k] = W1[k*16 + c]
    for (int i = t; i < HID * IN_CH; i += 256) {
        int k = i & 127, c = i >> 7;
        Wt[c * XP + k] = W1[k * HID + c];
    }
    int row0 = blockIdx.x * TR;
    // stage x tile: 32 rows x 32 float4, coalesced
    for (int i = t; i < TR * IN_CH / 4; i += 256) {
        int r = i >> 5, c4 = i & 31;
        int row = row0 + r;
        float4 v = (row < n) ? reinterpret_cast<const float4*>(x)[(size_t)row * 32 + c4]
                             : make_float4(0.f, 0.f, 0.f, 0.f);
        *reinterpret_cast<float4*>(&xs[r * XP + c4 * 4]) = v;
    }
    __syncthreads();
    int r = t >> 4;    // 0..15 -> rows r, r+16
    int c = t & 15;
    const float4* xr0 = reinterpret_cast<const float4*>(&xs[r * XP]);
    const float4* xr1 = reinterpret_cast<const float4*>(&xs[(r + 16) * XP]);
    const float4* wc  = reinterpret_cast<const float4*>(&Wt[c * XP]);
    float a0 = 0.f, a1 = 0.f;
#pragma unroll 4
    for (int k4 = 0; k4 < IN_CH / 4; ++k4) {
        float4 wv  = wc[k4];
        float4 v0  = xr0[k4];
        float4 v1  = xr1[k4];
        a0 = fmaf(v0.x, wv.x, a0); a0 = fmaf(v0.y, wv.y, a0);
        a0 = fmaf(v0.z, wv.z, a0); a0 = fmaf(v0.w, wv.w, a0);
        a1 = fmaf(v1.x, wv.x, a1); a1 = fmaf(v1.y, wv.y, a1);
        a1 = fmaf(v1.z, wv.z, a1); a1 = fmaf(v1.w, wv.w, a1);
    }
    int rr0 = row0 + r, rr1 = rr0 + 16;
    if (rr0 < n) h1p[(size_t)rr0 * HID + c] = f2bf(dinv[rr0] * a0);
    if (rr1 < n) h1p[(size_t)rr1 * HID + c] = f2bf(dinv[rr1] * a1);
}

// ---------------- gather layer 1: 4 threads/node (q=ch-half, p=edge-parity), shfl combine ----------------
__global__ __launch_bounds__(256) void k_gather1(const unsigned short* __restrict__ h1p,
                                                 const int* __restrict__ row_ptr,
                                                 const int* __restrict__ deg,
                                                 const float* __restrict__ dinv,
                                                 const int* __restrict__ col,
                                                 const float* __restrict__ b1,
                                                 unsigned short* __restrict__ h2p, int n) {
    int t = blockIdx.x * blockDim.x + threadIdx.x;
    int i = t >> 2;
    if (i >= n) return;
    int q = t & 1, p = (t >> 1) & 1;
    const uint4* hp = reinterpret_cast<const uint4*>(h1p);
    float a[8] = {0, 0, 0, 0, 0, 0, 0, 0};
    int j0 = row_ptr[i], j1 = j0 + deg[i];
    int j = j0 + p;
    for (; j + 6 < j1; j += 8) {
        int s0 = col[j], s1 = col[j + 2], s2 = col[j + 4], s3 = col[j + 6];
        uint4 v0 = hp[(size_t)s0 * 2 + q];
        uint4 v1 = hp[(size_t)s1 * 2 + q];
        uint4 v2 = hp[(size_t)s2 * 2 + q];
        uint4 v3 = hp[(size_t)s3 * 2 + q];
        acc8(v0, a); acc8(v1, a); acc8(v2, a); acc8(v3, a);
    }
    for (; j < j1; j += 2) acc8(hp[(size_t)col[j] * 2 + q], a);
    // combine edge-parity partners (lane^2 is same node, same q)
#pragma unroll
    for (int k = 0; k < 8; ++k) a[k] += __shfl_xor(a[k], 2);
    if (p == 0) {
        acc8(hp[(size_t)i * 2 + q], a);   // self-loop
        float di = dinv[i];
        float4 bl = *reinterpret_cast<const float4*>(&b1[q * 8]);
        float4 bh = *reinterpret_cast<const float4*>(&b1[q * 8 + 4]);
        float o[8];
        o[0] = di * fmaxf(fmaf(di, a[0], bl.x), 0.f);
        o[1] = di * fmaxf(fmaf(di, a[1], bl.y), 0.f);
        o[2] = di * fmaxf(fmaf(di, a[2], bl.z), 0.f);
        o[3] = di * fmaxf(fmaf(di, a[3], bl.w), 0.f);
        o[4] = di * fmaxf(fmaf(di, a[4], bh.x), 0.f);
        o[5] = di * fmaxf(fmaf(di, a[5], bh.y), 0.f);
        o[6] = di * fmaxf(fmaf(di, a[6], bh.z), 0.f);
        o[7] = di * fmaxf(fmaf(di, a[7], bh.w), 0.f);
        uint4 ov;
        ov.x = pack2(o[0], o[1]);
        ov.y = pack2(o[2], o[3]);
        ov.z = pack2(o[4], o[5]);
        ov.w = pack2(o[6], o[7]);
        reinterpret_cast<uint4*>(h2p)[(size_t)i * 2 + q] = ov;
    }
}

// ---------------- gather layer 2: 4 threads/node + fused (N x 16)@(16 x 64) + b2 ----------------
__global__ __launch_bounds__(256) void k_gather2_out(const unsigned short* __restrict__ h2p,
                                                     const int* __restrict__ row_ptr,
                                                     const int* __restrict__ deg,
                                                     const float* __restrict__ dinv,
                                                     const int* __restrict__ col,
                                                     const float* __restrict__ W2,
                                                     const float* __restrict__ b2,
                                                     float* __restrict__ out, int n) {
    __shared__ float Ws[HID * OUT_CH];    // 4 KB
    __shared__ float as[64][HID + 1];     // 4.4 KB
    int t = threadIdx.x;
    for (int i = t; i < HID * OUT_CH; i += 256) Ws[i] = W2[i];
    int nl = t >> 2;                       // 64 nodes/block
    int i = blockIdx.x * 64 + nl;
    int q = t & 1, p = (t >> 1) & 1;
    const uint4* hp = reinterpret_cast<const uint4*>(h2p);
    if (i < n) {
        float a[8] = {0, 0, 0, 0, 0, 0, 0, 0};
        int j0 = row_ptr[i], j1 = j0 + deg[i];
        int j = j0 + p;
        for (; j + 6 < j1; j += 8) {
            int s0 = col[j], s1 = col[j + 2], s2 = col[j + 4], s3 = col[j + 6];
            uint4 v0 = hp[(size_t)s0 * 2 + q];
            uint4 v1 = hp[(size_t)s1 * 2 + q];
            uint4 v2 = hp[(size_t)s2 * 2 + q];
            uint4 v3 = hp[(size_t)s3 * 2 + q];
            acc8(v0, a); acc8(v1, a); acc8(v2, a); acc8(v3, a);
        }
        for (; j < j1; j += 2) acc8(hp[(size_t)col[j] * 2 + q], a);
#pragma unroll
        for (int k = 0; k < 8; ++k) a[k] += __shfl_xor(a[k], 2);
        if (p == 0) {
            acc8(hp[(size_t)i * 2 + q], a);   // self
            float di = dinv[i];
#pragma unroll
            for (int k = 0; k < 8; ++k) as[nl][q * 8 + k] = di * a[k];
        }
    } else if (p == 0) {
#pragma unroll
        for (int k = 0; k < 8; ++k) as[nl][q * 8 + k] = 0.f;
    }
    __syncthreads();
    // epilogue: node nl, cols g*16 .. g*16+15
    int g = t & 3;
    float r[16];
#pragma unroll
    for (int c = 0; c < 16; ++c) r[c] = b2[g * 16 + c];
#pragma unroll
    for (int k = 0; k < HID; ++k) {
        float a = as[nl][k];
#pragma unroll
        for (int c = 0; c < 16; ++c) r[c] = fmaf(a, Ws[k * OUT_CH + g * 16 + c], r[c]);
    }
    if (i < n) {
        float* op = &out[(size_t)i * OUT_CH + g * 16];
#pragma unroll
        for (int c = 0; c < 16; c += 4)
            *reinterpret_cast<float4*>(&op[c]) = make_float4(r[c], r[c + 1], r[c + 2], r[c + 3]);
    }
}

extern "C" void kernel_launch(void* const* d_in, const int* in_sizes, int n_in,
                              void* d_out, int out_size, void* d_ws, size_t ws_size,
                              hipStream_t stream) {
    const float* x  = (const float*)d_in[0];
    const int*   ei = (const int*)d_in[1];
    const float* W1 = (const float*)d_in[2];
    const float* b1 = (const float*)d_in[3];
    const float* W2 = (const float*)d_in[4];
    const float* b2 = (const float*)d_in[5];
    float* out = (float*)d_out;

    const int* src = ei;
    const int* dst = ei + N_EDGES;

    // workspace layout (4B units)
    int*            cur     = (int*)d_ws;                          // [0, 256)
    int*            row_ptr = cur + 256;                           // [256, 100256)
    int*            deg     = row_ptr + N_NODES;                   // [100256, 200256)
    float*          dinv    = (float*)(deg + N_NODES);             // [200256, 300256)
    int*            col     = (int*)(dinv + N_NODES);              // [300256, 3828256)  196*18000
    unsigned short* h1p     = (unsigned short*)(col + NBUCK * BCAP);  // [3828256, 4628256) bf16 N*16 = 800000 words
    unsigned*       colp    = (unsigned*)((int*)h1p + 800000);     // [4628256, 8156256)  196*18000
    unsigned short* h2p     = (unsigned short*)colp;               // aliases colp (dead after k_build)

    // single-pass bucketed edge list (fixed-capacity runs; cur pre-set to b*BCAP)
    k_init_cur<<<1, 256, 0, stream>>>(cur);
    k_bucket<<<(N_EDGES + 4095) / 4096, 256, 0, stream>>>(src, dst, cur, colp, N_EDGES);
    // per-bucket counting sort -> full CSR + degrees + dinv
    k_build<<<NBUCK, 1024, 0, stream>>>(colp, cur, col, row_ptr, deg, dinv);

    // h1' = bf16(dinv * (x @ W1))
    k_gemm1<<<(N_NODES + TR - 1) / TR, 256, 0, stream>>>(x, W1, dinv, h1p, N_NODES);

    // layer 1: gather + bias + relu + pre-scale  (h2p aliases colp region; colp dead after k_build)
    k_gather1<<<((size_t)4 * N_NODES + 255) / 256, 256, 0, stream>>>(h1p, row_ptr, deg, dinv, col,
                                                                     b1, h2p, N_NODES);

    // layer 2: gather fused with final GEMM + bias
    k_gather2_out<<<(N_NODES + 63) / 64, 256, 0, stream>>>(h2p, row_ptr, deg, dinv, col, W2, b2,
                                                           out, N_NODES);
}